// Round 12
// baseline (1018.162 us; speedup 1.0000x reference)
//
#include <hip/hip_runtime.h>

#define NN 10000
#define NE 160000
#define DD 256
#define LEPS 1e-5f

typedef __attribute__((ext_vector_type(8))) short short8v;
typedef __attribute__((ext_vector_type(4))) float floatx4;
typedef unsigned short US;

static __device__ __forceinline__ US f2bf(float f){
  unsigned u = __builtin_bit_cast(unsigned, f);
  u += 0x7FFFu + ((u >> 16) & 1u);
  return (US)(u >> 16);
}
static __device__ __forceinline__ float bf2f(US s){
  unsigned u = ((unsigned)s) << 16;
  return __builtin_bit_cast(float, u);
}
// async global->LDS, 16B per lane (dest = wave-uniform base + lane*16 in our layouts)
static __device__ __forceinline__ void gl_lds16(const void* g, void* l){
  __builtin_amdgcn_global_load_lds((const __attribute__((address_space(1))) unsigned int*)g,
                                   (__attribute__((address_space(3))) unsigned int*)l, 16, 0, 0);
}

// ---- weight pack: W[K][256] f32 -> Bp[K/8][256][8] bf16 (fragment-ready)
__global__ void pack_k(const float* __restrict__ B, US* __restrict__ Bp, int Krows){
  int i = blockIdx.x * blockDim.x + threadIdx.x;
  int tot = (Krows >> 3) << 8;
  if (i >= tot) return;
  int kb = i >> 8, n = i & 255;
  union { US h[8]; uint4 q; } pk;
#pragma unroll
  for (int j = 0; j < 8; ++j) pk.h[j] = f2bf(B[(size_t)(kb*8 + j)*DD + n]);
  *(uint4*)(Bp + (size_t)i * 8) = pk.q;
}

// ---- MFMA GEMM, double-buffered (1 barrier/K-step), optional fused relu+LN epilogue
// MODE 0: A = p0  K=256 | MODE 2: A=[p0,p1] K=512 | MODE 3: A=[p0[i0],p0[i1],p1] K=768
// LNM 0: raw only | 1: LN(relu(x)) only | 2: both
template<int MODE, int LNM>
__global__ __launch_bounds__(256, 3)
void gemm_k(const float* __restrict__ p0, const float* __restrict__ p1,
            const int* __restrict__ idx0, const int* __restrict__ idx1,
            const US* __restrict__ Bp, const float* __restrict__ bias,
            const float* __restrict__ lg, const float* __restrict__ lb,
            float* __restrict__ Craw, float* __restrict__ Cln, int M, int K)
{
  __shared__ __align__(16) US Alds[2][64][40];
  __shared__ __align__(16) US Blds[2][8192];
  __shared__ float S1[4][64], S2[4][64];
  const int tid  = threadIdx.x;
  const int lane = tid & 63;
  const int wav  = tid >> 6;
  const int bm   = blockIdx.x * 64;

  floatx4 acc[4][4];
#pragma unroll
  for (int i = 0; i < 4; ++i)
#pragma unroll
    for (int j = 0; j < 4; ++j) acc[i][j] = (floatx4){0.f,0.f,0.f,0.f};

  const int ar = tid >> 2;
  const int ak = (tid & 3) << 3;
  int grow = bm + ar; if (grow > M - 1) grow = M - 1;

  const float* rA = nullptr; const float* rB = nullptr; const float* rC = nullptr;
  if (MODE == 0) { rA = p0 + (size_t)grow * DD; }
  else if (MODE == 2) { rA = p0 + (size_t)grow * DD; rB = p1 + (size_t)grow * DD; }
  else { int s0 = idx0[grow], s1 = idx1[grow];
         rA = p0 + (size_t)s0 * DD; rB = p0 + (size_t)s1 * DD; rC = p1 + (size_t)grow * DD; }

  const int rq = lane >> 4;
  const int cl = lane & 15;
  const int nsteps = K >> 5;

  float4 f0, f1;
  auto ldA = [&](int t){
    int kk = t*32 + ak;
    const float* s;
    if (MODE == 0) s = rA + kk;
    else if (MODE == 2) s = (kk < DD) ? (rA + kk) : (rB + kk - DD);
    else s = (kk < DD) ? (rA + kk) : (kk < 2*DD ? (rB + kk - DD) : (rC + kk - 2*DD));
    f0 = *(const float4*)s; f1 = *(const float4*)(s + 4);
  };
  auto packA = [&](int buf){
    union { US h[8]; uint4 q; } pk;
    pk.h[0]=f2bf(f0.x); pk.h[1]=f2bf(f0.y); pk.h[2]=f2bf(f0.z); pk.h[3]=f2bf(f0.w);
    pk.h[4]=f2bf(f1.x); pk.h[5]=f2bf(f1.y); pk.h[6]=f2bf(f1.z); pk.h[7]=f2bf(f1.w);
    *(uint4*)&Alds[buf][ar][ak] = pk.q;
  };
  auto stageB = [&](int t, int buf){
    const US* bs = Bp + (size_t)(t*4) * 2048;
#pragma unroll
    for (int u = 0; u < 4; ++u)
      gl_lds16(bs + (size_t)(tid + u*256)*8, &Blds[buf][(size_t)(tid + u*256)*8]);
  };

  // prologue: step 0 into buffer 0
  ldA(0); stageB(0, 0); packA(0);
  __syncthreads();

  int cur = 0;
  for (int t = 0; t < nsteps; ++t) {
    if (t + 1 < nsteps) { stageB(t + 1, cur ^ 1); ldA(t + 1); }
    short8v af[4], bfr[4];
#pragma unroll
    for (int i = 0; i < 4; ++i) af[i] = *(const short8v*)&Alds[cur][i*16 + cl][rq*8];
#pragma unroll
    for (int j = 0; j < 4; ++j) bfr[j] = *(const short8v*)&Blds[cur][(size_t)(rq*256 + wav*64 + j*16 + cl) * 8];
#pragma unroll
    for (int i = 0; i < 4; ++i)
#pragma unroll
      for (int j = 0; j < 4; ++j)
        acc[i][j] = __builtin_amdgcn_mfma_f32_16x16x32_bf16(af[i], bfr[j], acc[i][j], 0, 0, 0);
    if (t + 1 < nsteps) packA(cur ^ 1);
    __syncthreads();
    cur ^= 1;
  }

  if constexpr (LNM == 0) {
#pragma unroll
    for (int i = 0; i < 4; ++i)
#pragma unroll
      for (int r = 0; r < 4; ++r) {
        int gm = bm + i*16 + rq*4 + r;
        if (gm < M) {
#pragma unroll
          for (int j = 0; j < 4; ++j) {
            int n = wav*64 + j*16 + cl;
            Craw[(size_t)gm*DD + n] = acc[i][j][r] + bias[n];
          }
        }
      }
  } else {
#pragma unroll
    for (int i = 0; i < 4; ++i)
#pragma unroll
      for (int j = 0; j < 4; ++j) {
        int n = wav*64 + j*16 + cl;
        float bs = bias[n];
#pragma unroll
        for (int r = 0; r < 4; ++r) {
          int gm = bm + i*16 + rq*4 + r;
          float val = acc[i][j][r] + bs;
          if constexpr (LNM == 2) { if (gm < M) Craw[(size_t)gm*DD + n] = val; }
          acc[i][j][r] = fmaxf(val, 0.f);
        }
      }
#pragma unroll
    for (int i = 0; i < 4; ++i)
#pragma unroll
      for (int r = 0; r < 4; ++r) {
        float s1 = 0.f, s2 = 0.f;
#pragma unroll
        for (int j = 0; j < 4; ++j){ float v = acc[i][j][r]; s1 += v; s2 += v*v; }
#pragma unroll
        for (int o = 1; o < 16; o <<= 1){ s1 += __shfl_xor(s1, o, 64); s2 += __shfl_xor(s2, o, 64); }
        if (cl == 0){ S1[wav][i*16 + rq*4 + r] = s1; S2[wav][i*16 + rq*4 + r] = s2; }
      }
    __syncthreads();
#pragma unroll
    for (int i = 0; i < 4; ++i)
#pragma unroll
      for (int r = 0; r < 4; ++r) {
        int rr = i*16 + rq*4 + r;
        float t1 = S1[0][rr] + S1[1][rr] + S1[2][rr] + S1[3][rr];
        float t2 = S2[0][rr] + S2[1][rr] + S2[2][rr] + S2[3][rr];
        float mu = t1 * (1.f/256.f);
        float var = t2 * (1.f/256.f) - mu*mu;
        float rs = rsqrtf(fmaxf(var, 0.f) + LEPS);
        int gm = bm + i*16 + rq*4 + r;
        if (gm < M) {
#pragma unroll
          for (int j = 0; j < 4; ++j) {
            int n = wav*64 + j*16 + cl;
            Cln[(size_t)gm*DD + n] = (acc[i][j][r] - mu) * rs * lg[n] + lb[n];
          }
        }
      }
  }
}

// ---- fused K+V GEMM (A = [p0[idx0]*p1, p0[idx0]], K=512), double-buffered, CSR-ordered bf16 out
__global__ __launch_bounds__(256, 2)
void gemm_kv_k(const float* __restrict__ p0, const float* __restrict__ p1,
               const int* __restrict__ idx0,
               const US* __restrict__ BpK, const US* __restrict__ BpV,
               const float* __restrict__ biasK, const float* __restrict__ biasV,
               const int* __restrict__ eperm,
               US* __restrict__ Km, US* __restrict__ Vm, int M, int K)
{
  __shared__ __align__(16) US Alds[2][64][40];
  __shared__ __align__(16) US Blds[2][2][8192];   // [buf][K/V][32x256]
  const int tid  = threadIdx.x;
  const int lane = tid & 63;
  const int wav  = tid >> 6;
  const int bm   = blockIdx.x * 64;

  floatx4 accK[4][4], accV[4][4];
#pragma unroll
  for (int i = 0; i < 4; ++i)
#pragma unroll
    for (int j = 0; j < 4; ++j){ accK[i][j] = (floatx4){0.f,0.f,0.f,0.f}; accV[i][j] = (floatx4){0.f,0.f,0.f,0.f}; }

  const int ar = tid >> 2;
  const int ak = (tid & 3) << 3;
  int grow = bm + ar; if (grow > M - 1) grow = M - 1;
  int s = idx0[grow];
  const float* rA = p0 + (size_t)s * DD;
  const float* rB = p1 + (size_t)grow * DD;

  const int rq = lane >> 4;
  const int cl = lane & 15;
  const int nsteps = K >> 5;   // 16

  float4 f0, f1, g0, g1;
  auto ldA = [&](int t){
    int kk = t*32 + ak;
    if (kk < DD){
      f0 = *(const float4*)(rA + kk); f1 = *(const float4*)(rA + kk + 4);
      g0 = *(const float4*)(rB + kk); g1 = *(const float4*)(rB + kk + 4);
    } else {
      f0 = *(const float4*)(rA + kk - DD); f1 = *(const float4*)(rA + kk - DD + 4);
    }
  };
  auto packA = [&](int t, int buf){
    int kk = t*32 + ak;
    float4 x0 = f0, x1 = f1;
    if (kk < DD){
      x0.x*=g0.x; x0.y*=g0.y; x0.z*=g0.z; x0.w*=g0.w;
      x1.x*=g1.x; x1.y*=g1.y; x1.z*=g1.z; x1.w*=g1.w;
    }
    union { US h[8]; uint4 q; } pk;
    pk.h[0]=f2bf(x0.x); pk.h[1]=f2bf(x0.y); pk.h[2]=f2bf(x0.z); pk.h[3]=f2bf(x0.w);
    pk.h[4]=f2bf(x1.x); pk.h[5]=f2bf(x1.y); pk.h[6]=f2bf(x1.z); pk.h[7]=f2bf(x1.w);
    *(uint4*)&Alds[buf][ar][ak] = pk.q;
  };
  auto stageB = [&](int t, int buf){
    const US* bK = BpK + (size_t)(t*4) * 2048;
    const US* bV = BpV + (size_t)(t*4) * 2048;
#pragma unroll
    for (int u = 0; u < 4; ++u){
      gl_lds16(bK + (size_t)(tid + u*256)*8, &Blds[buf][0][(size_t)(tid + u*256)*8]);
      gl_lds16(bV + (size_t)(tid + u*256)*8, &Blds[buf][1][(size_t)(tid + u*256)*8]);
    }
  };

  ldA(0); stageB(0, 0); packA(0, 0);
  __syncthreads();

  int cur = 0;
  for (int t = 0; t < nsteps; ++t) {
    if (t + 1 < nsteps) { stageB(t + 1, cur ^ 1); ldA(t + 1); }
    short8v af[4], bK4[4], bV4[4];
#pragma unroll
    for (int i = 0; i < 4; ++i) af[i] = *(const short8v*)&Alds[cur][i*16 + cl][rq*8];
#pragma unroll
    for (int j = 0; j < 4; ++j){
      size_t bi = (size_t)(rq*256 + wav*64 + j*16 + cl) * 8;
      bK4[j] = *(const short8v*)&Blds[cur][0][bi];
      bV4[j] = *(const short8v*)&Blds[cur][1][bi];
    }
#pragma unroll
    for (int i = 0; i < 4; ++i)
#pragma unroll
      for (int j = 0; j < 4; ++j){
        accK[i][j] = __builtin_amdgcn_mfma_f32_16x16x32_bf16(af[i], bK4[j], accK[i][j], 0, 0, 0);
        accV[i][j] = __builtin_amdgcn_mfma_f32_16x16x32_bf16(af[i], bV4[j], accV[i][j], 0, 0, 0);
      }
    if (t + 1 < nsteps) packA(t + 1, cur ^ 1);
    __syncthreads();
    cur ^= 1;
  }

#pragma unroll
  for (int i = 0; i < 4; ++i)
#pragma unroll
    for (int r = 0; r < 4; ++r) {
      int gm = bm + i*16 + rq*4 + r;
      if (gm < M) {
        int pg = eperm[gm];
#pragma unroll
        for (int j = 0; j < 4; ++j) {
          int n = wav*64 + j*16 + cl;
          Km[(size_t)pg*DD + n] = f2bf(accK[i][j][r] + biasK[n]);
          Vm[(size_t)pg*DD + n] = f2bf(accV[i][j][r] + biasV[n]);
        }
      }
    }
}

// ---- CSR build over dst (emits edge->slot permutation)
__global__ void count_k(const int* __restrict__ dst, int* __restrict__ cnt, int e){
  int i = blockIdx.x * blockDim.x + threadIdx.x;
  if (i < e) atomicAdd(&cnt[dst[i]], 1);
}
__global__ void scan_k(const int* __restrict__ cnt, int* __restrict__ rp, int n){
  __shared__ int part[256];
  const int t = threadIdx.x;
  const int chunk = (n + 255) / 256;
  int lo = t * chunk, hi = lo + chunk; if (hi > n) hi = n; if (lo > n) lo = n;
  int s = 0;
  for (int i = lo; i < hi; ++i) s += cnt[i];
  part[t] = s; __syncthreads();
  if (t == 0){ int run = 0; for (int i = 0; i < 256; ++i){ int tmp = part[i]; part[i] = run; run += tmp; } rp[n] = run; }
  __syncthreads();
  int run = part[t];
  for (int i = lo; i < hi; ++i){ rp[i] = run; run += cnt[i]; }
}
__global__ void scatter_k(const int* __restrict__ dst, const int* __restrict__ rp,
                          int* __restrict__ pos, int* __restrict__ eperm, int e){
  int i = blockIdx.x * blockDim.x + threadIdx.x;
  if (i >= e) return;
  int d = dst[i];
  int p = atomicAdd(&pos[d], 1);
  eperm[i] = rp[d] + p;
}

// ---- per-node online softmax + aggregation; K/V in CSR order -> sequential reads
__global__ __launch_bounds__(256)
void node_agg_k(const int* __restrict__ rp,
                const float* __restrict__ Q, const US* __restrict__ Km,
                const US* __restrict__ Vm, float* __restrict__ agg)
{
  int d = blockIdx.x, f = threadIdx.x;
  int beg = rp[d], end = rp[d + 1];
  float q = Q[(size_t)d * DD + f];
  float m = -3.0e38f, z = 0.f, s = 0.f;
  for (int i = beg; i < end; ++i){
    float a  = q * bf2f(Km[(size_t)i * DD + f]);
    float vv = bf2f(Vm[(size_t)i * DD + f]);
    float mn = fmaxf(m, a);
    float sc = __expf(m - mn);
    float w  = __expf(a - mn);
    z = z * sc + w;
    s = s * sc + w * vv;
    m = mn;
  }
  agg[(size_t)d * DD + f] = (z > 0.f) ? (s / z) : 0.f;
}

__global__ void sentinel_k(int hostbits, float* out){
  int code = 0;
  if (hostbits & 1) code = 1;
  else if (hostbits & 2) code = 2;
  else if (hostbits & 4) code = 3;
  else if (hostbits & 8) code = 4;
  if (code) out[0] = (float)code * 1.0e6f;
}

extern "C" void kernel_launch(void* const* d_in, const int* in_sizes, int n_in,
                              void* d_out, int out_size, void* d_ws, size_t ws_size,
                              hipStream_t stream) {
  const float* node_h = (const float*)d_in[0];
  const float* edge_h = (const float*)d_in[1];
  const int*   src    = (const int*)d_in[2];
  const int*   dst    = (const int*)d_in[3];
  const float* Kw = (const float*)d_in[4];  const float* Kb = (const float*)d_in[5];
  const float* Vw = (const float*)d_in[6];  const float* Vb = (const float*)d_in[7];
  const float* Qw = (const float*)d_in[8];  const float* Qb = (const float*)d_in[9];
  const float* Ww = (const float*)d_in[10]; const float* Wb = (const float*)d_in[11];
  const float* Ew = (const float*)d_in[12]; const float* Eb = (const float*)d_in[13];
  const float* ln_g = (const float*)d_in[14];
  const float* ln_b = (const float*)d_in[15];

  char* w = (char*)d_ws; size_t off = 0;
  auto alloc = [&](size_t bytes)->char* {
    char* p = w + off; off += (bytes + 255) & ~(size_t)255; return p;
  };
  float* Q      = (float*)alloc((size_t)NN * DD * 4);
  float* agg    = (float*)alloc((size_t)NN * DD * 4);
  float* hn_new = (float*)alloc((size_t)NN * DD * 4);
  float* hn_cur = (float*)alloc((size_t)NN * DD * 4);
  US*    Kmat   = (US*)alloc((size_t)NE * DD * 2);
  US*    Vmat   = (US*)alloc((size_t)NE * DD * 2);
  float* he_cur = (float*)alloc((size_t)NE * DD * 4);
  US* BpK = (US*)alloc((size_t)512 * DD * 2);
  US* BpV = (US*)alloc((size_t)512 * DD * 2);
  US* BpQ = (US*)alloc((size_t)256 * DD * 2);
  US* BpW = (US*)alloc((size_t)512 * DD * 2);
  US* BpE = (US*)alloc((size_t)768 * DD * 2);
  int* cnt   = (int*)alloc((size_t)NN * 4);
  int* rp    = (int*)alloc((size_t)(NN + 1) * 4);
  int* pos   = (int*)alloc((size_t)NN * 4);
  int* eperm = (int*)alloc((size_t)NE * 4);

  float* out_hn = (float*)d_out;
  float* out_he = out_hn + (size_t)NN * DD;

  int hostbits = 0;
  {
    static const int exp_sizes[16] = {NN*DD, NE*DD, NE, NE, 2*512*DD, 2*DD, 2*512*DD, 2*DD,
                                      2*DD*DD, 2*DD, 2*512*DD, 2*DD, 2*768*DD, 2*DD, DD, DD};
    if (n_in != 16) hostbits |= 2;
    else { for (int i = 0; i < 16; ++i) if (in_sizes[i] != exp_sizes[i]) hostbits |= 2; }
    if (out_size != NN*DD + NE*DD) hostbits |= 4;
    if (off > ws_size) hostbits |= 1;
  }
  if (hostbits) {
    sentinel_k<<<1, 1, 0, stream>>>(hostbits, out_hn);
    return;
  }

  // CSR over dst (shared by both layers)
  hipMemsetAsync(cnt, 0, (size_t)NN * 4, stream);
  hipMemsetAsync(pos, 0, (size_t)NN * 4, stream);
  count_k<<<(NE + 255)/256, 256, 0, stream>>>(dst, cnt, NE);
  scan_k<<<1, 256, 0, stream>>>(cnt, rp, NN);
  scatter_k<<<(NE + 255)/256, 256, 0, stream>>>(dst, rp, pos, eperm, NE);

  const int gN = (NN + 63) / 64;   // 157
  const int gE = (NE + 63) / 64;   // 2500

  for (int l = 0; l < 2; ++l) {
    const float* hn_in = l ? hn_cur : node_h;
    const float* he_in = l ? he_cur : edge_h;
    float* hn_out = l ? out_hn : hn_cur;
    float* he_out = l ? out_he : he_cur;

    pack_k<<<(512*DD/8 + 255)/256, 256, 0, stream>>>(Kw + (size_t)l*512*DD, BpK, 512);
    pack_k<<<(512*DD/8 + 255)/256, 256, 0, stream>>>(Vw + (size_t)l*512*DD, BpV, 512);
    pack_k<<<(256*DD/8 + 255)/256, 256, 0, stream>>>(Qw + (size_t)l*256*DD, BpQ, 256);
    pack_k<<<(512*DD/8 + 255)/256, 256, 0, stream>>>(Ww + (size_t)l*512*DD, BpW, 512);
    pack_k<<<(768*DD/8 + 255)/256, 256, 0, stream>>>(Ew + (size_t)l*768*DD, BpE, 768);

    gemm_k<0, 0><<<gN, 256, 0, stream>>>(hn_in, nullptr, nullptr, nullptr,
                                         BpQ, Qb + (size_t)l*DD, nullptr, nullptr,
                                         Q, nullptr, NN, 256);
    gemm_kv_k<<<gE, 256, 0, stream>>>(hn_in, he_in, src, BpK, BpV,
                                      Kb + (size_t)l*DD, Vb + (size_t)l*DD,
                                      eperm, Kmat, Vmat, NE, 512);
    node_agg_k<<<NN, 256, 0, stream>>>(rp, Q, Kmat, Vmat, agg);
    gemm_k<2, 2><<<gN, 256, 0, stream>>>(agg, hn_in, nullptr, nullptr,
                                         BpW, Wb + (size_t)l*DD, ln_g, ln_b,
                                         hn_new, hn_out, NN, 512);
    gemm_k<3, 1><<<gE, 256, 0, stream>>>(hn_new, he_in, src, dst,
                                         BpE, Eb + (size_t)l*DD, ln_g, ln_b,
                                         nullptr, he_out, NE, 768);
  }

  if (hipGetLastError() != hipSuccess) {
    sentinel_k<<<1, 1, 0, stream>>>(8, out_hn);
  }
}

// Round 13
// 899.636 us; speedup vs baseline: 1.1317x; 1.1317x over previous
//
#include <hip/hip_runtime.h>

#define NN 10000
#define NE 160000
#define DD 256
#define LEPS 1e-5f

typedef __attribute__((ext_vector_type(8))) short short8v;
typedef __attribute__((ext_vector_type(4))) float floatx4;
typedef unsigned short US;

static __device__ __forceinline__ US f2bf(float f){
  unsigned u = __builtin_bit_cast(unsigned, f);
  u += 0x7FFFu + ((u >> 16) & 1u);
  return (US)(u >> 16);
}
static __device__ __forceinline__ float bf2f(US s){
  unsigned u = ((unsigned)s) << 16;
  return __builtin_bit_cast(float, u);
}

// ---- pack ALL layer weights in one launch into a fragment-ready arena.
// Arena kb-blocks (2048 US each): [0,32)Q [32,64)K1 [64,96)K2 [96,128)V1
// [128,160)V2 [160,224)W [224,256)E1 [256,288)E2 [288,320)E3
#define AOFF_Q  0
#define AOFF_K1 (32*2048)
#define AOFF_K2 (64*2048)
#define AOFF_V1 (96*2048)
#define AOFF_V2 (128*2048)
#define AOFF_W  (160*2048)
#define AOFF_E1 (224*2048)
#define AOFF_E2 (256*2048)
#define AOFF_E3 (288*2048)
__global__ void pack_all_k(const float* __restrict__ Qw, const float* __restrict__ Kw,
                           const float* __restrict__ Vw, const float* __restrict__ Ww,
                           const float* __restrict__ Ew, US* __restrict__ arena){
  int i = blockIdx.x * 256 + threadIdx.x;        // 0..81919
  int g = i >> 8, n = i & 255;
  const float* src; int row0;
  if      (g <  32){ src = Qw; row0 = g*8; }
  else if (g <  64){ src = Kw; row0 = (g-32)*8; }
  else if (g <  96){ src = Kw; row0 = 256 + (g-64)*8; }
  else if (g < 128){ src = Vw; row0 = (g-96)*8; }
  else if (g < 160){ src = Vw; row0 = 256 + (g-128)*8; }
  else if (g < 224){ src = Ww; row0 = (g-160)*8; }
  else if (g < 256){ src = Ew; row0 = (g-224)*8; }
  else if (g < 288){ src = Ew; row0 = 256 + (g-256)*8; }
  else             { src = Ew; row0 = 512 + (g-288)*8; }
  union { US h[8]; uint4 q; } pk;
#pragma unroll
  for (int j = 0; j < 8; ++j) pk.h[j] = f2bf(src[(size_t)(row0 + j)*DD + n]);
  *(uint4*)(arena + (size_t)g*2048 + n*8) = pk.q;
}

// ---- multi-output node GEMM: C_y[M][256] = A[M][256] @ B_y + bias_y, y = blockIdx.y
struct Tri { const US* bp; const float* bias; float* out; };
__global__ __launch_bounds__(256, 2)
void gemm_nmulti_k(const float* __restrict__ p0, Tri t0, Tri t1, Tri t2, int M)
{
  Tri t = (blockIdx.y == 0) ? t0 : (blockIdx.y == 1 ? t1 : t2);
  __shared__ __align__(16) US Alds[64][40];
  __shared__ __align__(16) US Blds[8192];
  const int tid  = threadIdx.x;
  const int lane = tid & 63;
  const int wav  = tid >> 6;
  const int bm   = blockIdx.x * 64;

  floatx4 acc[4][4];
#pragma unroll
  for (int i = 0; i < 4; ++i)
#pragma unroll
    for (int j = 0; j < 4; ++j) acc[i][j] = (floatx4){0.f,0.f,0.f,0.f};

  const int ar = tid >> 2;
  const int ak = (tid & 3) << 3;
  int grow = bm + ar; if (grow > M - 1) grow = M - 1;
  const float* rA = p0 + (size_t)grow * DD;
  const int rq = lane >> 4;
  const int cl = lane & 15;

  for (int k0 = 0; k0 < 256; k0 += 32) {
    const int kk = k0 + ak;
    float4 x0 = *(const float4*)(rA + kk);
    float4 x1 = *(const float4*)(rA + kk + 4);
    union { US h[8]; uint4 q; } pk;
    pk.h[0]=f2bf(x0.x); pk.h[1]=f2bf(x0.y); pk.h[2]=f2bf(x0.z); pk.h[3]=f2bf(x0.w);
    pk.h[4]=f2bf(x1.x); pk.h[5]=f2bf(x1.y); pk.h[6]=f2bf(x1.z); pk.h[7]=f2bf(x1.w);
    *(uint4*)&Alds[ar][ak] = pk.q;

    const uint4* bsrc = (const uint4*)(t.bp + (size_t)(k0 >> 3) * 2048);
    uint4* bdst = (uint4*)Blds;
#pragma unroll
    for (int u = 0; u < 4; ++u) bdst[tid + u*256] = bsrc[tid + u*256];
    __syncthreads();

    short8v af[4], bfr[4];
#pragma unroll
    for (int i = 0; i < 4; ++i) af[i] = *(const short8v*)&Alds[i*16 + cl][rq*8];
#pragma unroll
    for (int j = 0; j < 4; ++j) bfr[j] = *(const short8v*)&Blds[(size_t)(rq*256 + wav*64 + j*16 + cl) * 8];
#pragma unroll
    for (int i = 0; i < 4; ++i)
#pragma unroll
      for (int j = 0; j < 4; ++j)
        acc[i][j] = __builtin_amdgcn_mfma_f32_16x16x32_bf16(af[i], bfr[j], acc[i][j], 0, 0, 0);
    __syncthreads();
  }

#pragma unroll
  for (int i = 0; i < 4; ++i)
#pragma unroll
    for (int r = 0; r < 4; ++r) {
      int gm = bm + i*16 + rq*4 + r;
      if (gm < M) {
#pragma unroll
        for (int j = 0; j < 4; ++j) {
          int n = wav*64 + j*16 + cl;
          float b = t.bias ? t.bias[n] : 0.f;
          t.out[(size_t)gm*DD + n] = acc[i][j][r] + b;
        }
      }
    }
}

// ---- W GEMM: A=[agg,hn] K=512, raw + LN outputs (round-11 proven structure)
__global__ __launch_bounds__(256, 2)
void gemm_w_k(const float* __restrict__ p0, const float* __restrict__ p1,
              const US* __restrict__ Bp, const float* __restrict__ bias,
              const float* __restrict__ lg, const float* __restrict__ lb,
              float* __restrict__ Craw, float* __restrict__ Cln, int M)
{
  __shared__ __align__(16) US Alds[64][40];
  __shared__ __align__(16) US Blds[8192];
  __shared__ float S1[4][64], S2[4][64];
  const int tid  = threadIdx.x;
  const int lane = tid & 63;
  const int wav  = tid >> 6;
  const int bm   = blockIdx.x * 64;

  floatx4 acc[4][4];
#pragma unroll
  for (int i = 0; i < 4; ++i)
#pragma unroll
    for (int j = 0; j < 4; ++j) acc[i][j] = (floatx4){0.f,0.f,0.f,0.f};

  const int ar = tid >> 2;
  const int ak = (tid & 3) << 3;
  int grow = bm + ar; if (grow > M - 1) grow = M - 1;
  const float* rA = p0 + (size_t)grow * DD;
  const float* rB = p1 + (size_t)grow * DD;
  const int rq = lane >> 4;
  const int cl = lane & 15;

  for (int k0 = 0; k0 < 512; k0 += 32) {
    const int kk = k0 + ak;
    const float* s = (kk < DD) ? (rA + kk) : (rB + kk - DD);
    float4 x0 = *(const float4*)s;
    float4 x1 = *(const float4*)(s + 4);
    union { US h[8]; uint4 q; } pk;
    pk.h[0]=f2bf(x0.x); pk.h[1]=f2bf(x0.y); pk.h[2]=f2bf(x0.z); pk.h[3]=f2bf(x0.w);
    pk.h[4]=f2bf(x1.x); pk.h[5]=f2bf(x1.y); pk.h[6]=f2bf(x1.z); pk.h[7]=f2bf(x1.w);
    *(uint4*)&Alds[ar][ak] = pk.q;

    const uint4* bsrc = (const uint4*)(Bp + (size_t)(k0 >> 3) * 2048);
    uint4* bdst = (uint4*)Blds;
#pragma unroll
    for (int u = 0; u < 4; ++u) bdst[tid + u*256] = bsrc[tid + u*256];
    __syncthreads();

    short8v af[4], bfr[4];
#pragma unroll
    for (int i = 0; i < 4; ++i) af[i] = *(const short8v*)&Alds[i*16 + cl][rq*8];
#pragma unroll
    for (int j = 0; j < 4; ++j) bfr[j] = *(const short8v*)&Blds[(size_t)(rq*256 + wav*64 + j*16 + cl) * 8];
#pragma unroll
    for (int i = 0; i < 4; ++i)
#pragma unroll
      for (int j = 0; j < 4; ++j)
        acc[i][j] = __builtin_amdgcn_mfma_f32_16x16x32_bf16(af[i], bfr[j], acc[i][j], 0, 0, 0);
    __syncthreads();
  }

#pragma unroll
  for (int i = 0; i < 4; ++i)
#pragma unroll
    for (int j = 0; j < 4; ++j) {
      int n = wav*64 + j*16 + cl;
      float bs = bias[n];
#pragma unroll
      for (int r = 0; r < 4; ++r) {
        int gm = bm + i*16 + rq*4 + r;
        float val = acc[i][j][r] + bs;
        if (gm < M) Craw[(size_t)gm*DD + n] = val;
        acc[i][j][r] = fmaxf(val, 0.f);
      }
    }
#pragma unroll
  for (int i = 0; i < 4; ++i)
#pragma unroll
    for (int r = 0; r < 4; ++r) {
      float s1 = 0.f, s2 = 0.f;
#pragma unroll
      for (int j = 0; j < 4; ++j){ float v = acc[i][j][r]; s1 += v; s2 += v*v; }
#pragma unroll
      for (int o = 1; o < 16; o <<= 1){ s1 += __shfl_xor(s1, o, 64); s2 += __shfl_xor(s2, o, 64); }
      if (cl == 0){ S1[wav][i*16 + rq*4 + r] = s1; S2[wav][i*16 + rq*4 + r] = s2; }
    }
  __syncthreads();
#pragma unroll
  for (int i = 0; i < 4; ++i)
#pragma unroll
    for (int r = 0; r < 4; ++r) {
      int rr = i*16 + rq*4 + r;
      float t1 = S1[0][rr] + S1[1][rr] + S1[2][rr] + S1[3][rr];
      float t2 = S2[0][rr] + S2[1][rr] + S2[2][rr] + S2[3][rr];
      float mu = t1 * (1.f/256.f);
      float var = t2 * (1.f/256.f) - mu*mu;
      float rs = rsqrtf(fmaxf(var, 0.f) + LEPS);
      int gm = bm + i*16 + rq*4 + r;
      if (gm < M) {
#pragma unroll
        for (int j = 0; j < 4; ++j) {
          int n = wav*64 + j*16 + cl;
          Cln[(size_t)gm*DD + n] = (acc[i][j][r] - mu) * rs * lg[n] + lb[n];
        }
      }
    }
}

// ---- edge K+V GEMM: A = src_h∘h_e (K=256), dual B, epilogue += KN/VN[src], CSR-slot bf16 out
__global__ __launch_bounds__(256, 2)
void gemm_kve_k(const float* __restrict__ p0, const float* __restrict__ p1,
                const int* __restrict__ srcI,
                const US* __restrict__ BpK, const US* __restrict__ BpV,
                const float* __restrict__ KN, const float* __restrict__ VN,
                const int* __restrict__ eperm,
                US* __restrict__ Km, US* __restrict__ Vm, int M)
{
  __shared__ __align__(16) US Alds[64][40];
  __shared__ __align__(16) US BldsK[8192];
  __shared__ __align__(16) US BldsV[8192];
  const int tid  = threadIdx.x;
  const int lane = tid & 63;
  const int wav  = tid >> 6;
  const int bm   = blockIdx.x * 64;

  floatx4 accK[4][4], accV[4][4];
#pragma unroll
  for (int i = 0; i < 4; ++i)
#pragma unroll
    for (int j = 0; j < 4; ++j){ accK[i][j] = (floatx4){0.f,0.f,0.f,0.f}; accV[i][j] = (floatx4){0.f,0.f,0.f,0.f}; }

  const int ar = tid >> 2;
  const int ak = (tid & 3) << 3;
  int grow = bm + ar; if (grow > M - 1) grow = M - 1;
  int s = srcI[grow];
  const float* rA = p0 + (size_t)s * DD;
  const float* rB = p1 + (size_t)grow * DD;
  const int rq = lane >> 4;
  const int cl = lane & 15;

  for (int k0 = 0; k0 < 256; k0 += 32) {
    const int kk = k0 + ak;
    float4 x0 = *(const float4*)(rA + kk);
    float4 x1 = *(const float4*)(rA + kk + 4);
    float4 m0 = *(const float4*)(rB + kk);
    float4 m1 = *(const float4*)(rB + kk + 4);
    x0.x*=m0.x; x0.y*=m0.y; x0.z*=m0.z; x0.w*=m0.w;
    x1.x*=m1.x; x1.y*=m1.y; x1.z*=m1.z; x1.w*=m1.w;
    union { US h[8]; uint4 q; } pk;
    pk.h[0]=f2bf(x0.x); pk.h[1]=f2bf(x0.y); pk.h[2]=f2bf(x0.z); pk.h[3]=f2bf(x0.w);
    pk.h[4]=f2bf(x1.x); pk.h[5]=f2bf(x1.y); pk.h[6]=f2bf(x1.z); pk.h[7]=f2bf(x1.w);
    *(uint4*)&Alds[ar][ak] = pk.q;

    const uint4* bsK = (const uint4*)(BpK + (size_t)(k0 >> 3) * 2048);
    const uint4* bsV = (const uint4*)(BpV + (size_t)(k0 >> 3) * 2048);
    uint4* bdK = (uint4*)BldsK; uint4* bdV = (uint4*)BldsV;
#pragma unroll
    for (int u = 0; u < 4; ++u){ bdK[tid + u*256] = bsK[tid + u*256]; bdV[tid + u*256] = bsV[tid + u*256]; }
    __syncthreads();

    short8v af[4], bK4[4], bV4[4];
#pragma unroll
    for (int i = 0; i < 4; ++i) af[i] = *(const short8v*)&Alds[i*16 + cl][rq*8];
#pragma unroll
    for (int j = 0; j < 4; ++j){
      size_t bi = (size_t)(rq*256 + wav*64 + j*16 + cl) * 8;
      bK4[j] = *(const short8v*)&BldsK[bi];
      bV4[j] = *(const short8v*)&BldsV[bi];
    }
#pragma unroll
    for (int i = 0; i < 4; ++i)
#pragma unroll
      for (int j = 0; j < 4; ++j){
        accK[i][j] = __builtin_amdgcn_mfma_f32_16x16x32_bf16(af[i], bK4[j], accK[i][j], 0, 0, 0);
        accV[i][j] = __builtin_amdgcn_mfma_f32_16x16x32_bf16(af[i], bV4[j], accV[i][j], 0, 0, 0);
      }
    __syncthreads();
  }

#pragma unroll
  for (int i = 0; i < 4; ++i)
#pragma unroll
    for (int r = 0; r < 4; ++r) {
      int gm = bm + i*16 + rq*4 + r;
      if (gm < M) {
        int pg = eperm[gm];
        int sg = srcI[gm];
        const float* kn = KN + (size_t)sg * DD;
        const float* vn = VN + (size_t)sg * DD;
#pragma unroll
        for (int j = 0; j < 4; ++j) {
          int n = wav*64 + j*16 + cl;
          Km[(size_t)pg*DD + n] = f2bf(accK[i][j][r] + kn[n]);
          Vm[(size_t)pg*DD + n] = f2bf(accV[i][j][r] + vn[n]);
        }
      }
    }
}

// ---- edge E GEMM: A = h_e (K=256, pure stream), epilogue += EN1[src]+EN2[dst], fused relu+LN
__global__ __launch_bounds__(256, 2)
void gemm_e_k(const float* __restrict__ he, const int* __restrict__ srcI,
              const int* __restrict__ dstI, const US* __restrict__ Bp,
              const float* __restrict__ EN1, const float* __restrict__ EN2,
              const float* __restrict__ lg, const float* __restrict__ lb,
              float* __restrict__ Cln, int M)
{
  __shared__ __align__(16) US Alds[64][40];
  __shared__ __align__(16) US Blds[8192];
  __shared__ float S1[4][64], S2[4][64];
  const int tid  = threadIdx.x;
  const int lane = tid & 63;
  const int wav  = tid >> 6;
  const int bm   = blockIdx.x * 64;

  floatx4 acc[4][4];
#pragma unroll
  for (int i = 0; i < 4; ++i)
#pragma unroll
    for (int j = 0; j < 4; ++j) acc[i][j] = (floatx4){0.f,0.f,0.f,0.f};

  const int ar = tid >> 2;
  const int ak = (tid & 3) << 3;
  int grow = bm + ar; if (grow > M - 1) grow = M - 1;
  const float* rA = he + (size_t)grow * DD;
  const int rq = lane >> 4;
  const int cl = lane & 15;

  for (int k0 = 0; k0 < 256; k0 += 32) {
    const int kk = k0 + ak;
    float4 x0 = *(const float4*)(rA + kk);
    float4 x1 = *(const float4*)(rA + kk + 4);
    union { US h[8]; uint4 q; } pk;
    pk.h[0]=f2bf(x0.x); pk.h[1]=f2bf(x0.y); pk.h[2]=f2bf(x0.z); pk.h[3]=f2bf(x0.w);
    pk.h[4]=f2bf(x1.x); pk.h[5]=f2bf(x1.y); pk.h[6]=f2bf(x1.z); pk.h[7]=f2bf(x1.w);
    *(uint4*)&Alds[ar][ak] = pk.q;

    const uint4* bsrc = (const uint4*)(Bp + (size_t)(k0 >> 3) * 2048);
    uint4* bdst = (uint4*)Blds;
#pragma unroll
    for (int u = 0; u < 4; ++u) bdst[tid + u*256] = bsrc[tid + u*256];
    __syncthreads();

    short8v af[4], bfr[4];
#pragma unroll
    for (int i = 0; i < 4; ++i) af[i] = *(const short8v*)&Alds[i*16 + cl][rq*8];
#pragma unroll
    for (int j = 0; j < 4; ++j) bfr[j] = *(const short8v*)&Blds[(size_t)(rq*256 + wav*64 + j*16 + cl) * 8];
#pragma unroll
    for (int i = 0; i < 4; ++i)
#pragma unroll
      for (int j = 0; j < 4; ++j)
        acc[i][j] = __builtin_amdgcn_mfma_f32_16x16x32_bf16(af[i], bfr[j], acc[i][j], 0, 0, 0);
    __syncthreads();
  }

  // epilogue: add EN1[src], EN2[dst]; relu; LN
#pragma unroll
  for (int i = 0; i < 4; ++i)
#pragma unroll
    for (int r = 0; r < 4; ++r) {
      int gm = bm + i*16 + rq*4 + r;
      int gmc = (gm < M) ? gm : (M - 1);
      const float* e1 = EN1 + (size_t)srcI[gmc] * DD;
      const float* e2 = EN2 + (size_t)dstI[gmc] * DD;
#pragma unroll
      for (int j = 0; j < 4; ++j) {
        int n = wav*64 + j*16 + cl;
        float val = acc[i][j][r] + e1[n] + e2[n];
        acc[i][j][r] = fmaxf(val, 0.f);
      }
    }
#pragma unroll
  for (int i = 0; i < 4; ++i)
#pragma unroll
    for (int r = 0; r < 4; ++r) {
      float s1 = 0.f, s2 = 0.f;
#pragma unroll
      for (int j = 0; j < 4; ++j){ float v = acc[i][j][r]; s1 += v; s2 += v*v; }
#pragma unroll
      for (int o = 1; o < 16; o <<= 1){ s1 += __shfl_xor(s1, o, 64); s2 += __shfl_xor(s2, o, 64); }
      if (cl == 0){ S1[wav][i*16 + rq*4 + r] = s1; S2[wav][i*16 + rq*4 + r] = s2; }
    }
  __syncthreads();
#pragma unroll
  for (int i = 0; i < 4; ++i)
#pragma unroll
    for (int r = 0; r < 4; ++r) {
      int rr = i*16 + rq*4 + r;
      float t1 = S1[0][rr] + S1[1][rr] + S1[2][rr] + S1[3][rr];
      float t2 = S2[0][rr] + S2[1][rr] + S2[2][rr] + S2[3][rr];
      float mu = t1 * (1.f/256.f);
      float var = t2 * (1.f/256.f) - mu*mu;
      float rs = rsqrtf(fmaxf(var, 0.f) + LEPS);
      int gm = bm + i*16 + rq*4 + r;
      if (gm < M) {
#pragma unroll
        for (int j = 0; j < 4; ++j) {
          int n = wav*64 + j*16 + cl;
          Cln[(size_t)gm*DD + n] = (acc[i][j][r] - mu) * rs * lg[n] + lb[n];
        }
      }
    }
}

// ---- CSR build over dst (emits edge->slot permutation)
__global__ void count_k(const int* __restrict__ dst, int* __restrict__ cnt, int e){
  int i = blockIdx.x * blockDim.x + threadIdx.x;
  if (i < e) atomicAdd(&cnt[dst[i]], 1);
}
__global__ void scan_k(const int* __restrict__ cnt, int* __restrict__ rp, int n){
  __shared__ int part[256];
  const int t = threadIdx.x;
  const int chunk = (n + 255) / 256;
  int lo = t * chunk, hi = lo + chunk; if (hi > n) hi = n; if (lo > n) lo = n;
  int s = 0;
  for (int i = lo; i < hi; ++i) s += cnt[i];
  part[t] = s; __syncthreads();
  if (t == 0){ int run = 0; for (int i = 0; i < 256; ++i){ int tmp = part[i]; part[i] = run; run += tmp; } rp[n] = run; }
  __syncthreads();
  int run = part[t];
  for (int i = lo; i < hi; ++i){ rp[i] = run; run += cnt[i]; }
}
__global__ void scatter_k(const int* __restrict__ dst, const int* __restrict__ rp,
                          int* __restrict__ pos, int* __restrict__ eperm, int e){
  int i = blockIdx.x * blockDim.x + threadIdx.x;
  if (i >= e) return;
  int d = dst[i];
  int p = atomicAdd(&pos[d], 1);
  eperm[i] = rp[d] + p;
}

// ---- per-node online softmax + aggregation; K/V in CSR order -> sequential reads
__global__ __launch_bounds__(256)
void node_agg_k(const int* __restrict__ rp,
                const float* __restrict__ Q, const US* __restrict__ Km,
                const US* __restrict__ Vm, float* __restrict__ agg)
{
  int d = blockIdx.x, f = threadIdx.x;
  int beg = rp[d], end = rp[d + 1];
  float q = Q[(size_t)d * DD + f];
  float m = -3.0e38f, z = 0.f, s = 0.f;
  for (int i = beg; i < end; ++i){
    float a  = q * bf2f(Km[(size_t)i * DD + f]);
    float vv = bf2f(Vm[(size_t)i * DD + f]);
    float mn = fmaxf(m, a);
    float sc = __expf(m - mn);
    float w  = __expf(a - mn);
    z = z * sc + w;
    s = s * sc + w * vv;
    m = mn;
  }
  agg[(size_t)d * DD + f] = (z > 0.f) ? (s / z) : 0.f;
}

__global__ void sentinel_k(int hostbits, float* out){
  int code = 0;
  if (hostbits & 1) code = 1;
  else if (hostbits & 2) code = 2;
  else if (hostbits & 4) code = 3;
  else if (hostbits & 8) code = 4;
  if (code) out[0] = (float)code * 1.0e6f;
}

extern "C" void kernel_launch(void* const* d_in, const int* in_sizes, int n_in,
                              void* d_out, int out_size, void* d_ws, size_t ws_size,
                              hipStream_t stream) {
  const float* node_h = (const float*)d_in[0];
  const float* edge_h = (const float*)d_in[1];
  const int*   src    = (const int*)d_in[2];
  const int*   dst    = (const int*)d_in[3];
  const float* Kw = (const float*)d_in[4];  const float* Kb = (const float*)d_in[5];
  const float* Vw = (const float*)d_in[6];  const float* Vb = (const float*)d_in[7];
  const float* Qw = (const float*)d_in[8];  const float* Qb = (const float*)d_in[9];
  const float* Ww = (const float*)d_in[10]; const float* Wb = (const float*)d_in[11];
  const float* Ew = (const float*)d_in[12]; const float* Eb = (const float*)d_in[13];
  const float* ln_g = (const float*)d_in[14];
  const float* ln_b = (const float*)d_in[15];

  char* w = (char*)d_ws; size_t off = 0;
  auto alloc = [&](size_t bytes)->char* {
    char* p = w + off; off += (bytes + 255) & ~(size_t)255; return p;
  };
  float* Q      = (float*)alloc((size_t)NN * DD * 4);
  float* agg    = (float*)alloc((size_t)NN * DD * 4);
  float* hn_new = (float*)alloc((size_t)NN * DD * 4);
  float* hn_cur = (float*)alloc((size_t)NN * DD * 4);
  float* KN     = (float*)alloc((size_t)NN * DD * 4);
  float* VN     = (float*)alloc((size_t)NN * DD * 4);
  float* EN1    = (float*)alloc((size_t)NN * DD * 4);
  float* EN2    = (float*)alloc((size_t)NN * DD * 4);
  US*    Kmat   = (US*)alloc((size_t)NE * DD * 2);
  US*    Vmat   = (US*)alloc((size_t)NE * DD * 2);
  float* he_cur = (float*)alloc((size_t)NE * DD * 4);
  US*    arena  = (US*)alloc((size_t)320 * 2048 * 2);
  int* cnt   = (int*)alloc((size_t)NN * 4);
  int* rp    = (int*)alloc((size_t)(NN + 1) * 4);
  int* pos   = (int*)alloc((size_t)NN * 4);
  int* eperm = (int*)alloc((size_t)NE * 4);

  float* out_hn = (float*)d_out;
  float* out_he = out_hn + (size_t)NN * DD;

  int hostbits = 0;
  {
    static const int exp_sizes[16] = {NN*DD, NE*DD, NE, NE, 2*512*DD, 2*DD, 2*512*DD, 2*DD,
                                      2*DD*DD, 2*DD, 2*512*DD, 2*DD, 2*768*DD, 2*DD, DD, DD};
    if (n_in != 16) hostbits |= 2;
    else { for (int i = 0; i < 16; ++i) if (in_sizes[i] != exp_sizes[i]) hostbits |= 2; }
    if (out_size != NN*DD + NE*DD) hostbits |= 4;
    if (off > ws_size) hostbits |= 1;
  }
  if (hostbits) {
    sentinel_k<<<1, 1, 0, stream>>>(hostbits, out_hn);
    return;
  }

  // CSR over dst (shared by both layers)
  hipMemsetAsync(cnt, 0, (size_t)NN * 4, stream);
  hipMemsetAsync(pos, 0, (size_t)NN * 4, stream);
  count_k<<<(NE + 255)/256, 256, 0, stream>>>(dst, cnt, NE);
  scan_k<<<1, 256, 0, stream>>>(cnt, rp, NN);
  scatter_k<<<(NE + 255)/256, 256, 0, stream>>>(dst, rp, pos, eperm, NE);

  const int gN = (NN + 63) / 64;   // 157
  const int gE = (NE + 63) / 64;   // 2500

  for (int l = 0; l < 2; ++l) {
    const float* hn_in = l ? hn_cur : node_h;
    const float* he_in = l ? he_cur : edge_h;
    float* hn_out = l ? out_hn : hn_cur;
    float* he_out = l ? out_he : he_cur;

    pack_all_k<<<320, 256, 0, stream>>>(Qw + (size_t)l*256*DD, Kw + (size_t)l*512*DD,
                                        Vw + (size_t)l*512*DD, Ww + (size_t)l*512*DD,
                                        Ew + (size_t)l*768*DD, arena);

    // node-side: Q = hn@Qw+Qb ; KN = hn@Kw2+Kb ; VN = hn@Vw2+Vb
    {
      Tri tQ{arena + AOFF_Q,  Qb + (size_t)l*DD, Q};
      Tri tK{arena + AOFF_K2, Kb + (size_t)l*DD, KN};
      Tri tV{arena + AOFF_V2, Vb + (size_t)l*DD, VN};
      gemm_nmulti_k<<<dim3(gN, 3), 256, 0, stream>>>(hn_in, tQ, tK, tV, NN);
    }
    // edge-side K/V: (src∘he)@{Kw1,Vw1} + {KN,VN}[src] -> CSR slots (bf16)
    gemm_kve_k<<<gE, 256, 0, stream>>>(hn_in, he_in, src,
                                       arena + AOFF_K1, arena + AOFF_V1,
                                       KN, VN, eperm, Kmat, Vmat, NE);
    node_agg_k<<<NN, 256, 0, stream>>>(rp, Q, Kmat, Vmat, agg);
    // W: [agg,hn]@Ww+Wb -> raw hn_new + LN hn_out
    gemm_w_k<<<gN, 256, 0, stream>>>(agg, hn_in, arena + AOFF_W, Wb + (size_t)l*DD,
                                     ln_g, ln_b, hn_new, hn_out, NN);
    // node-side E: EN1 = hn_new@Ew1+Eb ; EN2 = hn_new@Ew2
    {
      Tri t1{arena + AOFF_E1, Eb + (size_t)l*DD, EN1};
      Tri t2{arena + AOFF_E2, nullptr, EN2};
      gemm_nmulti_k<<<dim3(gN, 2), 256, 0, stream>>>(hn_new, t1, t2, t2, NN);
    }
    // edge-side E: he@Ew3 + EN1[src] + EN2[dst] -> relu+LN -> he_out
    gemm_e_k<<<gE, 256, 0, stream>>>(he_in, src, dst, arena + AOFF_E3,
                                     EN1, EN2, ln_g, ln_b, he_out, NE);
  }

  if (hipGetLastError() != hipSuccess) {
    sentinel_k<<<1, 1, 0, stream>>>(8, out_hn);
  }
}